// Round 9
// baseline (426.197 us; speedup 1.0000x reference)
//
#include <hip/hip_runtime.h>

typedef unsigned short u16;
typedef __bf16 bf16x8 __attribute__((ext_vector_type(8)));
typedef unsigned short u16x8 __attribute__((ext_vector_type(8)));
typedef float f32x4 __attribute__((ext_vector_type(4)));

#define M_ROWS 8232
#define SEQ 1029
#define NPREF 5
#define DIMN 1024
#define NH 16
#define HD 64

// Q pre-scale = 0.125 * log2(e): lets attn use exp2 directly (saves a v_mul per score)
#define QSCALE 0.18033688011112042f
// 16 * log2(e)
#define EXPBIAS 23.083120654223414f

// k_attn LDS row pad (u16 units). 76 -> row stride 152B = 38 banks = 6 mod 32;
// fr*6 mod 32 is distinct for fr=0..15, so every b128 frag read/write spreads
// evenly (8 accesses/bank = minimum). The old 72 (stride = 4 mod 32) aliased
// fr and fr+8 -> 8.7M SQ_LDS_BANK_CONFLICT cycles/dispatch (r8 counters).
#define APAD 76

// raw barrier for attn: LDS-only wait, no vmem drain
#define BAR_LGKM asm volatile("s_waitcnt lgkmcnt(0)\ns_barrier" ::: "memory")

typedef __attribute__((address_space(1))) const unsigned char as1_u8;
typedef __attribute__((address_space(3))) unsigned char as3_u8;

// async global->LDS, 16B per lane. LDS dest is wave-uniform base + lane*16.
__device__ __forceinline__ void gload_lds16(const u16* g, u16* l) {
  __builtin_amdgcn_global_load_lds((as1_u8*)g, (as3_u8*)l, 16, 0, 0);
}

__device__ __forceinline__ u16 f2bf(float f) {
  unsigned u = __float_as_uint(f);
  u += 0x7fffu + ((u >> 16) & 1u);
  return (u16)(u >> 16);
}

__device__ __forceinline__ unsigned pk2bf(float lo, float hi) {
  unsigned ul = __float_as_uint(lo);
  unsigned uh = __float_as_uint(hi);
  ul += 0x7fffu + ((ul >> 16) & 1u);
  uh += 0x7fffu + ((uh >> 16) & 1u);
  return __builtin_amdgcn_perm(uh, ul, 0x07060302u);
}

// ---------------- x (fp32) -> Xpack (bf16, fragment-major lines) ----------------
__global__ __launch_bounds__(256) void k_pack_x(const float* __restrict__ x, u16* __restrict__ Xp) {
  int cb = blockIdx.x;  // 0..3
  int rb = blockIdx.y;  // 0..129
  __shared__ u16 Tl[64 * 264];
  int t = threadIdx.x;
#pragma unroll
  for (int p = 0; p < 16; ++p) {
    int idx = p * 256 + t;
    int row = idx >> 6;
    int c4 = idx & 63;
    int grow = rb * 64 + row; if (grow >= M_ROWS) grow = M_ROWS - 1;
    float4 v = *reinterpret_cast<const float4*>(x + (size_t)grow * DIMN + cb * 256 + c4 * 4);
    ushort4 o;
    o.x = f2bf(v.x); o.y = f2bf(v.y); o.z = f2bf(v.z); o.w = f2bf(v.w);
    *reinterpret_cast<ushort4*>(&Tl[row * 264 + c4 * 4]) = o;
  }
  __syncthreads();
  int wv = t >> 6, lane = t & 63;
  int mt = rb >> 1, g = rb & 1;
#pragma unroll
  for (int li = 0; li < 8; ++li) {
    int ll = wv * 8 + li;
    int i = ll >> 3;
    int kkl = ll & 7;
    int row = i * 16 + (lane & 15);
    int col = kkl * 32 + (lane >> 4) * 8;
    uint4 d = *reinterpret_cast<const uint4*>(&Tl[row * 264 + col]);
    size_t line = ((size_t)(mt * 2 + g) * 4 + i) * 32 + (cb * 8 + kkl);
    *reinterpret_cast<uint4*>(Xp + line * 512 + lane * 8) = d;
  }
}

// ---------------- W (fp32 [K][N]) -> Wpack (bf16, fragment-major lines) ----------------
__global__ __launch_bounds__(256) void k_wt(const float* __restrict__ W0, const float* __restrict__ W1,
                                            const float* __restrict__ W2, const float* __restrict__ W3,
                                            u16* __restrict__ P0, u16* __restrict__ P1,
                                            u16* __restrict__ P2, u16* __restrict__ P3) {
  const float* W; u16* P;
  switch (blockIdx.z) {
    case 0: W = W0; P = P0; break;
    case 1: W = W1; P = P1; break;
    case 2: W = W2; P = P2; break;
    default: W = W3; P = P3; break;
  }
  __shared__ float tile[64 * 68];
  int t = threadIdx.x;
  int kb = blockIdx.x, nb = blockIdx.y;
#pragma unroll
  for (int p = 0; p < 16; ++p) {
    int idx = p * 256 + t;
    int row = idx >> 6, col = idx & 63;
    tile[row * 68 + col] = W[(size_t)(kb * 64 + row) * DIMN + nb * 64 + col];
  }
  __syncthreads();
  int wv = t >> 6, lane = t & 63;
#pragma unroll
  for (int li = 0; li < 2; ++li) {
    int ll = wv * 2 + li;
    int jg = ll >> 1, kkl = ll & 1;
    int n = jg * 16 + (lane & 15);
    int kc = kkl * 32 + (lane >> 4) * 8;
    u16 buf[8];
#pragma unroll
    for (int dk = 0; dk < 8; ++dk) buf[dk] = f2bf(tile[(kc + dk) * 68 + n]);
    size_t line = (size_t)(nb * 4 + jg) * 32 + kb * 2 + kkl;
    *reinterpret_cast<uint4*>(P + line * 512 + lane * 8) = *reinterpret_cast<const uint4*>(buf);
  }
}

#define MM16(AF, BF) do { \
  _Pragma("unroll") for (int i_ = 0; i_ < 4; ++i_) \
  _Pragma("unroll") for (int j_ = 0; j_ < 4; ++j_) \
    acc[i_][j_] = __builtin_amdgcn_mfma_f32_16x16x32_bf16(AF[i_], BF[j_], acc[i_][j_], 0, 0, 0); \
} while (0)

// stage tile tt into buffer bufI: each wave DMAs its 4 owned lines (4KB)
#define STAGE(bufI, tt) do { \
  _Pragma("unroll") for (int q_ = 0; q_ < 4; ++q_) \
    gload_lds16(gsrc[q_] + (size_t)(tt) * 512, Sb + (bufI) * 8192 + (wv * 4 + q_) * 512); \
} while (0)

// Pipelined K-loop (r5-verified best): 3 LDS buffers (48 KiB -> 3 blocks/CU),
// depth-2 prefetch, ONE barrier per K-step, STAGE issued AFTER the barrier.
// WAR: STAGE(t+2) writes buf (t-1)%3, whose readers all passed the top-of-t
// barrier before any wave issues STAGE(t+2). RAW: staging wave waits vmcnt(4)
// before the iter-t barrier, draining buf-t's DMA. Tail: last STAGE at kk=29;
// kk=31 waits vmcnt(0) -> zero outstanding LDS-DMA at exit (in-flight DMA at
// s_endpgm hangs). setprio(1) around MFMA cluster (T5, multi-block/CU regime).
#define KLOOP32 do { \
  STAGE(0, 0); \
  STAGE(1, 1); \
  _Pragma("unroll") \
  for (int kk = 0; kk < 32; ++kk) { \
    if (kk < 31) { \
      asm volatile("s_waitcnt vmcnt(4)" ::: "memory"); \
    } else { \
      asm volatile("s_waitcnt vmcnt(0)" ::: "memory"); \
    } \
    __builtin_amdgcn_s_barrier(); \
    asm volatile("" ::: "memory"); \
    if (kk + 2 < 32) STAGE((kk + 2) % 3, kk + 2); \
    const u16* rd_ = Sb + (kk % 3) * 8192; \
    bf16x8 a_[4], bfr_[4]; \
    _Pragma("unroll") for (int i_ = 0; i_ < 4; ++i_) { \
      a_[i_]   = *reinterpret_cast<const bf16x8*>(rd_ + (ga * 4 + i_) * 512 + lane * 8); \
      bfr_[i_] = *reinterpret_cast<const bf16x8*>(rd_ + (8 + gb * 4 + i_) * 512 + lane * 8); \
    } \
    __builtin_amdgcn_s_setprio(1); \
    MM16(a_, bfr_); \
    __builtin_amdgcn_s_setprio(0); \
    asm volatile("" ::: "memory"); \
  } \
} while (0)

// ---------------- fused QKV projection GEMM: 128x128, LDS-staged, pipelined (r5 form) ----------------
// grid 1728: xcd=bid&7; within XCD: nt fastest (A-tile sharers), then mtq (A stream),
// then mode slowest (2MB weight pack L2-resident per phase). mt = mtq*8+xcd.
__global__ __launch_bounds__(256) void k_qkv(
    const u16* __restrict__ Xp,
    const u16* __restrict__ Pq, const u16* __restrict__ Pk, const u16* __restrict__ Pv,
    const float* __restrict__ bq, const float* __restrict__ bv,
    const float* __restrict__ rc, const float* __restrict__ rs,
    u16* __restrict__ Qg, u16* __restrict__ Kg, u16* __restrict__ Vg)
{
  int bid = blockIdx.x;
  int xcd = bid & 7;
  int s = bid >> 3;           // 0..215
  int nt = s & 7;
  int s2 = s >> 3;            // 0..26
  int mode = s2 / 9;
  int mtq = s2 - mode * 9;
  int mt = mtq * 8 + xcd;
  if (mt >= 65) return;
  const u16* Wp = (mode == 0) ? Pq : (mode == 1) ? Pk : Pv;
  u16* dst = (mode == 0) ? Qg : (mode == 1) ? Kg : Vg;
  int m0 = mt * 128, n0 = nt * 128;

  int t = threadIdx.x, lane = t & 63, wv = t >> 6;
  int fr = lane & 15, quad = lane >> 4;
  int ga = wv >> 1, gb = wv & 1;
  int wm = ga * 64, wn = gb * 64;

  __shared__ u16 S[3 * 16 * 512];   // 3 buffers x 16 lines x 1KB = 48 KiB
  u16* Sb = S;

  // staging: wave wv owns lines wv*4 .. wv*4+3. Lines 0..7 = A(ga,i), 8..15 = B(gb,j).
  const u16* gsrc[4];
#pragma unroll
  for (int q = 0; q < 4; ++q) {
    int ls = wv * 4 + q;
    const u16* base;
    int lineIdx;
    if (ls < 8) {
      int g = ls >> 2, i = ls & 3;
      base = Xp; lineIdx = ((mt * 2 + g) * 4 + i) * 32;
    } else {
      int l2 = ls - 8;
      int g = l2 >> 2, j = l2 & 3;
      base = Wp; lineIdx = ((nt * 2 + g) * 4 + j) * 32;
    }
    gsrc[q] = base + (size_t)lineIdx * 512 + lane * 8;
  }

  f32x4 zero4 = {0.f, 0.f, 0.f, 0.f};
  f32x4 acc[4][4];
#pragma unroll
  for (int i = 0; i < 4; ++i)
#pragma unroll
    for (int j = 0; j < 4; ++j) acc[i][j] = zero4;

  KLOOP32;

  int h = (n0 + wn) >> 6;
#pragma unroll
  for (int i = 0; i < 4; ++i) {
    int rowbase = m0 + wm + i * 16 + quad * 4;
#pragma unroll
    for (int r = 0; r < 4; ++r) {
      int row = rowbase + r;
      if (row >= M_ROWS) continue;
      int b = row / SEQ;
      int sI = row - b * SEQ;
#pragma unroll
      for (int j = 0; j < 4; ++j) {
        int d = j * 16 + fr;
        float v = acc[i][j][r];
        float outv;
        if (mode == 2) {
          outv = v + bv[n0 + wn + d];
        } else {
          float vb = v;
          int jp = j ^ 2;
          float pv = acc[i][jp][r];
          if (mode == 0) {
            vb += bq[n0 + wn + d];
            pv += bq[n0 + wn + (jp * 16 + fr)];
          }
          if (sI >= NPREF) {
            int p = sI - NPREF;
            float c = rc[p * HD + d];
            float sn = rs[p * HD + d];
            float rot = (d < 32) ? -pv : pv;
            outv = vb * c + rot * sn;
          } else {
            outv = vb;
          }
          if (mode == 0) outv *= QSCALE;  // 0.125 * log2(e); attn uses exp2
        }
        dst[((size_t)(b * NH + h) * SEQ + sI) * HD + d] = f2bf(outv);
      }
    }
  }
}

// ---------------- flash attention; epilogue writes AO in packed-fragment layout ----------------
__global__ __launch_bounds__(256) void k_attn(
    const u16* __restrict__ Qg, const u16* __restrict__ Kg, const u16* __restrict__ Vg,
    u16* __restrict__ AOp)
{
  int bh = blockIdx.x;
  int mtb = blockIdx.y;
  int q0 = mtb * 128;
  int b = bh >> 4, h = bh & 15;
  const size_t base = (size_t)bh * SEQ * HD;

  __shared__ u16 KV[128 * APAD];
  __shared__ u16 Ps[4][32 * APAD];
  u16* Ks = KV;
  u16* Vt = KV + 64 * APAD;

  int t = threadIdx.x, lane = t & 63, wv = t >> 6;
  int fr = lane & 15, quad = lane >> 4;

  int ki = t >> 2;
  int kc0 = (t & 3) * 16;
  int vs0 = (t & 31) * 2;
  int vdo = (t >> 5) * 8;

  bf16x8 qf[2][2];
#pragma unroll
  for (int qt = 0; qt < 2; ++qt) {
#pragma unroll
    for (int st = 0; st < 2; ++st) {
      int row = q0 + wv * 32 + qt * 16 + fr;
      if (row >= SEQ) row = SEQ - 1;
      qf[qt][st] = *reinterpret_cast<const bf16x8*>(Qg + base + (size_t)row * HD + st * 32 + quad * 8);
    }
  }

  u16x8 one16 = {0x3F80, 0x3F80, 0x3F80, 0x3F80, 0x3F80, 0x3F80, 0x3F80, 0x3F80};
  bf16x8 vone = __builtin_bit_cast(bf16x8, one16);

  f32x4 zero4 = {0.f, 0.f, 0.f, 0.f};
  f32x4 o[2][5];
#pragma unroll
  for (int qt = 0; qt < 2; ++qt)
#pragma unroll
    for (int di = 0; di < 5; ++di) o[qt][di] = zero4;

  uint4 krA0, krA1, vrA0, vrA1;
  {
    int kr = ki; if (kr >= SEQ) kr = SEQ - 1;
    const u16* ksrc = Kg + base + (size_t)kr * HD;
    krA0 = *reinterpret_cast<const uint4*>(ksrc + kc0);
    krA1 = *reinterpret_cast<const uint4*>(ksrc + kc0 + 8);
    int r0 = vs0; if (r0 >= SEQ) r0 = SEQ - 1;
    int r1 = vs0 + 1; if (r1 >= SEQ) r1 = SEQ - 1;
    vrA0 = *reinterpret_cast<const uint4*>(Vg + base + (size_t)r0 * HD + vdo);
    vrA1 = *reinterpret_cast<const uint4*>(Vg + base + (size_t)r1 * HD + vdo);
  }

  for (int kt = 0; kt < 17; ++kt) {
    int k0 = kt * 64;
    BAR_LGKM;
    *reinterpret_cast<uint4*>(&Ks[ki * APAD + kc0]) = krA0;
    *reinterpret_cast<uint4*>(&Ks[ki * APAD + kc0 + 8]) = krA1;
    {
      u16 v0[8], v1[8];
      *reinterpret_cast<uint4*>(v0) = vrA0;
      *reinterpret_cast<uint4*>(v1) = vrA1;
#pragma unroll
      for (int j = 0; j < 8; ++j) {
        unsigned pk = (unsigned)v0[j] | ((unsigned)v1[j] << 16);
        *reinterpret_cast<unsigned*>(&Vt[(vdo + j) * APAD + vs0]) = pk;
      }
    }
    if (kt < 16) {
      int kn = k0 + 64;
      int kr = kn + ki; if (kr >= SEQ) kr = SEQ - 1;
      const u16* ksrc = Kg + base + (size_t)kr * HD;
      krA0 = *reinterpret_cast<const uint4*>(ksrc + kc0);
      krA1 = *reinterpret_cast<const uint4*>(ksrc + kc0 + 8);
      int r0 = kn + vs0; if (r0 >= SEQ) r0 = SEQ - 1;
      int r1 = kn + vs0 + 1; if (r1 >= SEQ) r1 = SEQ - 1;
      vrA0 = *reinterpret_cast<const uint4*>(Vg + base + (size_t)r0 * HD + vdo);
      vrA1 = *reinterpret_cast<const uint4*>(Vg + base + (size_t)r1 * HD + vdo);
    }
    BAR_LGKM;

    f32x4 sc[4][2];
#pragma unroll
    for (int mi = 0; mi < 4; ++mi)
#pragma unroll
      for (int qt = 0; qt < 2; ++qt) sc[mi][qt] = zero4;
    __builtin_amdgcn_s_setprio(1);
#pragma unroll
    for (int st = 0; st < 2; ++st) {
#pragma unroll
      for (int mi = 0; mi < 4; ++mi) {
        bf16x8 kf = *reinterpret_cast<const bf16x8*>(&Ks[(mi * 16 + fr) * APAD + st * 32 + quad * 8]);
#pragma unroll
        for (int qt = 0; qt < 2; ++qt)
          sc[mi][qt] = __builtin_amdgcn_mfma_f32_16x16x32_bf16(kf, qf[qt][st], sc[mi][qt], 0, 0, 0);
      }
    }
    __builtin_amdgcn_s_setprio(0);

    bool last = (kt == 16);
#pragma unroll
    for (int qt = 0; qt < 2; ++qt) {
#pragma unroll
      for (int mi = 0; mi < 4; ++mi) {
        float p0, p1, p2, p3;
        {
          float s0v = sc[mi][qt][0], s1v = sc[mi][qt][1], s2v = sc[mi][qt][2], s3v = sc[mi][qt][3];
          if (last) {
            int kc = mi * 16 + quad * 4;
            if (kc + 0 >= NPREF) s0v = -1e30f;
            if (kc + 1 >= NPREF) s1v = -1e30f;
            if (kc + 2 >= NPREF) s2v = -1e30f;
            if (kc + 3 >= NPREF) s3v = -1e30f;
          }
          // scores were computed with Q pre-scaled by 0.125*log2(e):
          // exp2(s' - 16*log2(e)) == exp(s_orig*0.125 - 16) exactly.
          p0 = exp2f(s0v - EXPBIAS);
          p1 = exp2f(s1v - EXPBIAS);
          p2 = exp2f(s2v - EXPBIAS);
          p3 = exp2f(s3v - EXPBIAS);
        }
        unsigned d0 = pk2bf(p0, p1);
        unsigned d1 = pk2bf(p2, p3);
        uint2 w; w.x = d0; w.y = d1;
        *reinterpret_cast<uint2*>(&Ps[wv][(qt * 16 + fr) * APAD + mi * 16 + quad * 4]) = w;
      }
    }

#pragma unroll
    for (int st = 0; st < 2; ++st) {
      bf16x8 pf[2];
#pragma unroll
      for (int qt = 0; qt < 2; ++qt)
        pf[qt] = *reinterpret_cast<const bf16x8*>(&Ps[wv][(qt * 16 + fr) * APAD + st * 32 + quad * 8]);
      __builtin_amdgcn_s_setprio(1);
#pragma unroll
      for (int di = 0; di < 4; ++di) {
        bf16x8 vf = *reinterpret_cast<const bf16x8*>(&Vt[(di * 16 + fr) * APAD + st * 32 + quad * 8]);
#pragma unroll
        for (int qt = 0; qt < 2; ++qt)
          o[qt][di] = __builtin_amdgcn_mfma_f32_16x16x32_bf16(pf[qt], vf, o[qt][di], 0, 0, 0);
      }
#pragma unroll
      for (int qt = 0; qt < 2; ++qt)
        o[qt][4] = __builtin_amdgcn_mfma_f32_16x16x32_bf16(pf[qt], vone, o[qt][4], 0, 0, 0);
      __builtin_amdgcn_s_setprio(0);
    }
  }

  __syncthreads();
#pragma unroll
  for (int qt = 0; qt < 2; ++qt) {
#pragma unroll
    for (int r = 0; r < 4; ++r) {
      int rowl = wv * 32 + qt * 16 + quad * 4 + r;
      bool valid = (q0 + rowl) < SEQ;
      float inv = valid ? (1.f / o[qt][4][r]) : 0.f;
#pragma unroll
      for (int di = 0; di < 4; ++di)
        KV[rowl * APAD + di * 16 + fr] = f2bf(o[qt][di][r] * inv);
    }
  }
  __syncthreads();
#pragma unroll
  for (int li = 0; li < 4; ++li) {
    int ll = wv * 4 + li;
    int g = ll >> 3, i = (ll >> 1) & 3, kkl = ll & 1;
    int rowl = g * 64 + i * 16 + (lane & 15);
    int col = kkl * 32 + (lane >> 4) * 8;
    uint4 d = *reinterpret_cast<const uint4*>(&KV[rowl * APAD + col]);
    size_t line = ((size_t)((b * 9 + mtb) * 2 + g) * 4 + i) * 32 + (h * 2 + kkl);
    *reinterpret_cast<uint4*>(AOp + line * 512 + lane * 8) = d;
  }
}

// ---------------- output GEMM: LDS-staged, pipelined (r5 form -- measured ~15us
// better than reg-streaming via r5-vs-r7 totals with k_qkv pinned) ----------------
// grid 576: xcd=bid&7; s=bid>>3: nt fastest, mtq next; mid = mtq*8+xcd (exactly 72).
__global__ __launch_bounds__(256) void k_out(
    const u16* __restrict__ AOp, const u16* __restrict__ Po,
    const float* __restrict__ bo, float* __restrict__ Out)
{
  int bid = blockIdx.x;
  int xcd = bid & 7;
  int s = bid >> 3;           // 0..71
  int nt = s & 7;
  int mtq = s >> 3;           // 0..8
  int mid = mtq * 8 + xcd;    // 0..71
  int b = mid / 9, mtb = mid - b * 9;
  int n0 = nt * 128;

  int t = threadIdx.x, lane = t & 63, wv = t >> 6;
  int fr = lane & 15, quad = lane >> 4;
  int ga = wv >> 1, gb = wv & 1;
  int wm = ga * 64, wn = gb * 64;

  __shared__ u16 S[3 * 16 * 512];   // 48 KiB
  u16* Sb = S;

  const u16* gsrc[4];
#pragma unroll
  for (int q = 0; q < 4; ++q) {
    int ls = wv * 4 + q;
    const u16* base;
    int lineIdx;
    if (ls < 8) {
      int g = ls >> 2, i = ls & 3;
      base = AOp; lineIdx = ((mid * 2 + g) * 4 + i) * 32;
    } else {
      int l2 = ls - 8;
      int g = l2 >> 2, j = l2 & 3;
      base = Po; lineIdx = ((nt * 2 + g) * 4 + j) * 32;
    }
    gsrc[q] = base + (size_t)lineIdx * 512 + lane * 8;
  }

  f32x4 zero4 = {0.f, 0.f, 0.f, 0.f};
  f32x4 acc[4][4];
#pragma unroll
  for (int i = 0; i < 4; ++i)
#pragma unroll
    for (int j = 0; j < 4; ++j) acc[i][j] = zero4;

  KLOOP32;

#pragma unroll
  for (int i = 0; i < 4; ++i) {
    int rowbase = mtb * 128 + wm + i * 16 + quad * 4;
#pragma unroll
    for (int r = 0; r < 4; ++r) {
      int rowl = rowbase + r;
      if (rowl >= SEQ) continue;
      size_t row = (size_t)b * SEQ + rowl;
#pragma unroll
      for (int j = 0; j < 4; ++j) {
        int col = n0 + wn + j * 16 + fr;
        Out[row * DIMN + col] = acc[i][j][r] + bo[col];
      }
    }
  }
}

extern "C" void kernel_launch(void* const* d_in, const int* in_sizes, int n_in,
                              void* d_out, int out_size, void* d_ws, size_t ws_size,
                              hipStream_t stream)
{
  const float* x  = (const float*)d_in[0];
  const float* rc = (const float*)d_in[1];
  const float* rs = (const float*)d_in[2];
  const float* Wq = (const float*)d_in[3];
  const float* bq = (const float*)d_in[4];
  const float* Wk = (const float*)d_in[5];
  const float* Wv = (const float*)d_in[6];
  const float* bv = (const float*)d_in[7];
  const float* Wo = (const float*)d_in[8];
  const float* bo = (const float*)d_in[9];
  float* Out = (float*)d_out;

  u16* p = (u16*)d_ws;
  u16* Xp = p; p += (size_t)16640 * 512;
  u16* Pq = p; p += (size_t)2048 * 512;
  u16* Pk = p; p += (size_t)2048 * 512;
  u16* Pv = p; p += (size_t)2048 * 512;
  u16* Po = p; p += (size_t)2048 * 512;
  u16* Qg = p; p += (size_t)M_ROWS * DIMN;
  u16* Kg = p; p += (size_t)M_ROWS * DIMN;
  u16* Vg = p; p += (size_t)M_ROWS * DIMN;
  u16* AOp = Xp;  // aliases dead Xp+Pq after k_qkv

  dim3 gx(4, 130);
  k_pack_x<<<gx, 256, 0, stream>>>(x, Xp);
  dim3 gt(16, 16, 4);
  k_wt<<<gt, 256, 0, stream>>>(Wq, Wk, Wv, Wo, Pq, Pk, Pv, Po);
  k_qkv<<<1728, 256, 0, stream>>>(Xp, Pq, Pk, Pv, bq, bv, rc, rs, Qg, Kg, Vg);
  dim3 g2(128, 9);
  k_attn<<<g2, 256, 0, stream>>>(Qg, Kg, Vg, AOp);
  k_out<<<576, 256, 0, stream>>>(AOp, Po, bo, Out);
}

// Round 10
// 307.870 us; speedup vs baseline: 1.3843x; 1.3843x over previous
//
#include <hip/hip_runtime.h>

typedef unsigned short u16;
typedef __bf16 bf16x8 __attribute__((ext_vector_type(8)));
typedef unsigned short u16x8 __attribute__((ext_vector_type(8)));
typedef float f32x4 __attribute__((ext_vector_type(4)));

#define M_ROWS 8232
#define SEQ 1029
#define NPREF 5
#define DIMN 1024
#define NH 16
#define HD 64

// Q pre-scale = 0.125 * log2(e): lets attn use exp2 directly (saves a v_mul per score)
#define QSCALE 0.18033688011112042f
// 16 * log2(e)
#define EXPBIAS 23.083120654223414f

// k_attn LDS row pad: 72 u16 = 144 B. MUST stay 16B-aligned (multiple of 8 u16):
// r9 measured APAD=76 (152B, 8-mod-16) at 2x attn time -- misaligned b128.
// Bank analysis: at 72, every b128 access lands 8 lanes/bank-group = bandwidth
// minimum; the ~8.7M SQ_LDS_BANK_CONFLICT it reports is non-actionable.
#define APAD 72

// raw barrier for attn: LDS-only wait, no vmem drain
#define BAR_LGKM asm volatile("s_waitcnt lgkmcnt(0)\ns_barrier" ::: "memory")

typedef __attribute__((address_space(1))) const unsigned char as1_u8;
typedef __attribute__((address_space(3))) unsigned char as3_u8;

// async global->LDS, 16B per lane. LDS dest is wave-uniform base + lane*16.
__device__ __forceinline__ void gload_lds16(const u16* g, u16* l) {
  __builtin_amdgcn_global_load_lds((as1_u8*)g, (as3_u8*)l, 16, 0, 0);
}

__device__ __forceinline__ u16 f2bf(float f) {
  unsigned u = __float_as_uint(f);
  u += 0x7fffu + ((u >> 16) & 1u);
  return (u16)(u >> 16);
}

// packed f32x2 -> bf16x2 (RNE), single VOP3 instruction; replaces the 6-op
// software rounding pair in the VALU-bound attn softmax (r8: VALUBusy 56%).
__device__ __forceinline__ unsigned cvtpk(float lo, float hi) {
  unsigned r;
  asm("v_cvt_pk_bf16_f32 %0, %1, %2" : "=v"(r) : "v"(lo), "v"(hi));
  return r;
}

// ---------------- x (fp32) -> Xpack (bf16, fragment-major lines) ----------------
__global__ __launch_bounds__(256) void k_pack_x(const float* __restrict__ x, u16* __restrict__ Xp) {
  int cb = blockIdx.x;  // 0..3
  int rb = blockIdx.y;  // 0..129
  __shared__ u16 Tl[64 * 264];
  int t = threadIdx.x;
#pragma unroll
  for (int p = 0; p < 16; ++p) {
    int idx = p * 256 + t;
    int row = idx >> 6;
    int c4 = idx & 63;
    int grow = rb * 64 + row; if (grow >= M_ROWS) grow = M_ROWS - 1;
    float4 v = *reinterpret_cast<const float4*>(x + (size_t)grow * DIMN + cb * 256 + c4 * 4);
    ushort4 o;
    o.x = f2bf(v.x); o.y = f2bf(v.y); o.z = f2bf(v.z); o.w = f2bf(v.w);
    *reinterpret_cast<ushort4*>(&Tl[row * 264 + c4 * 4]) = o;
  }
  __syncthreads();
  int wv = t >> 6, lane = t & 63;
  int mt = rb >> 1, g = rb & 1;
#pragma unroll
  for (int li = 0; li < 8; ++li) {
    int ll = wv * 8 + li;
    int i = ll >> 3;
    int kkl = ll & 7;
    int row = i * 16 + (lane & 15);
    int col = kkl * 32 + (lane >> 4) * 8;
    uint4 d = *reinterpret_cast<const uint4*>(&Tl[row * 264 + col]);
    size_t line = ((size_t)(mt * 2 + g) * 4 + i) * 32 + (cb * 8 + kkl);
    *reinterpret_cast<uint4*>(Xp + line * 512 + lane * 8) = d;
  }
}

// ---------------- W (fp32 [K][N]) -> Wpack (bf16, fragment-major lines) ----------------
__global__ __launch_bounds__(256) void k_wt(const float* __restrict__ W0, const float* __restrict__ W1,
                                            const float* __restrict__ W2, const float* __restrict__ W3,
                                            u16* __restrict__ P0, u16* __restrict__ P1,
                                            u16* __restrict__ P2, u16* __restrict__ P3) {
  const float* W; u16* P;
  switch (blockIdx.z) {
    case 0: W = W0; P = P0; break;
    case 1: W = W1; P = P1; break;
    case 2: W = W2; P = P2; break;
    default: W = W3; P = P3; break;
  }
  __shared__ float tile[64 * 68];
  int t = threadIdx.x;
  int kb = blockIdx.x, nb = blockIdx.y;
#pragma unroll
  for (int p = 0; p < 16; ++p) {
    int idx = p * 256 + t;
    int row = idx >> 6, col = idx & 63;
    tile[row * 68 + col] = W[(size_t)(kb * 64 + row) * DIMN + nb * 64 + col];
  }
  __syncthreads();
  int wv = t >> 6, lane = t & 63;
#pragma unroll
  for (int li = 0; li < 2; ++li) {
    int ll = wv * 2 + li;
    int jg = ll >> 1, kkl = ll & 1;
    int n = jg * 16 + (lane & 15);
    int kc = kkl * 32 + (lane >> 4) * 8;
    u16 buf[8];
#pragma unroll
    for (int dk = 0; dk < 8; ++dk) buf[dk] = f2bf(tile[(kc + dk) * 68 + n]);
    size_t line = (size_t)(nb * 4 + jg) * 32 + kb * 2 + kkl;
    *reinterpret_cast<uint4*>(P + line * 512 + lane * 8) = *reinterpret_cast<const uint4*>(buf);
  }
}

#define MM16(AF, BF) do { \
  _Pragma("unroll") for (int i_ = 0; i_ < 4; ++i_) \
  _Pragma("unroll") for (int j_ = 0; j_ < 4; ++j_) \
    acc[i_][j_] = __builtin_amdgcn_mfma_f32_16x16x32_bf16(AF[i_], BF[j_], acc[i_][j_], 0, 0, 0); \
} while (0)

// stage tile tt into buffer bufI: each wave DMAs its 4 owned lines (4KB)
#define STAGE(bufI, tt) do { \
  _Pragma("unroll") for (int q_ = 0; q_ < 4; ++q_) \
    gload_lds16(gsrc[q_] + (size_t)(tt) * 512, Sb + (bufI) * 8192 + (wv * 4 + q_) * 512); \
} while (0)

// Pipelined K-loop (r5-verified best): 3 LDS buffers (48 KiB -> 3 blocks/CU),
// depth-2 prefetch, ONE barrier per K-step, STAGE issued AFTER the barrier.
// WAR: STAGE(t+2) writes buf (t-1)%3, whose readers all passed the top-of-t
// barrier before any wave issues STAGE(t+2). RAW: staging wave waits vmcnt(4)
// before the iter-t barrier, draining buf-t's DMA. Tail: last STAGE at kk=29;
// kk=31 waits vmcnt(0) -> zero outstanding LDS-DMA at exit (in-flight DMA at
// s_endpgm hangs). setprio(1) around MFMA cluster (T5, multi-block/CU regime).
#define KLOOP32 do { \
  STAGE(0, 0); \
  STAGE(1, 1); \
  _Pragma("unroll") \
  for (int kk = 0; kk < 32; ++kk) { \
    if (kk < 31) { \
      asm volatile("s_waitcnt vmcnt(4)" ::: "memory"); \
    } else { \
      asm volatile("s_waitcnt vmcnt(0)" ::: "memory"); \
    } \
    __builtin_amdgcn_s_barrier(); \
    asm volatile("" ::: "memory"); \
    if (kk + 2 < 32) STAGE((kk + 2) % 3, kk + 2); \
    const u16* rd_ = Sb + (kk % 3) * 8192; \
    bf16x8 a_[4], bfr_[4]; \
    _Pragma("unroll") for (int i_ = 0; i_ < 4; ++i_) { \
      a_[i_]   = *reinterpret_cast<const bf16x8*>(rd_ + (ga * 4 + i_) * 512 + lane * 8); \
      bfr_[i_] = *reinterpret_cast<const bf16x8*>(rd_ + (8 + gb * 4 + i_) * 512 + lane * 8); \
    } \
    __builtin_amdgcn_s_setprio(1); \
    MM16(a_, bfr_); \
    __builtin_amdgcn_s_setprio(0); \
    asm volatile("" ::: "memory"); \
  } \
} while (0)

// ---------------- fused QKV projection GEMM: 128x128, LDS-staged, pipelined (r5 form) ----------------
// grid 1728: xcd=bid&7; within XCD: nt fastest (A-tile sharers), then mtq (A stream),
// then mode slowest (2MB weight pack L2-resident per phase). mt = mtq*8+xcd.
__global__ __launch_bounds__(256) void k_qkv(
    const u16* __restrict__ Xp,
    const u16* __restrict__ Pq, const u16* __restrict__ Pk, const u16* __restrict__ Pv,
    const float* __restrict__ bq, const float* __restrict__ bv,
    const float* __restrict__ rc, const float* __restrict__ rs,
    u16* __restrict__ Qg, u16* __restrict__ Kg, u16* __restrict__ Vg)
{
  int bid = blockIdx.x;
  int xcd = bid & 7;
  int s = bid >> 3;           // 0..215
  int nt = s & 7;
  int s2 = s >> 3;            // 0..26
  int mode = s2 / 9;
  int mtq = s2 - mode * 9;
  int mt = mtq * 8 + xcd;
  if (mt >= 65) return;
  const u16* Wp = (mode == 0) ? Pq : (mode == 1) ? Pk : Pv;
  u16* dst = (mode == 0) ? Qg : (mode == 1) ? Kg : Vg;
  int m0 = mt * 128, n0 = nt * 128;

  int t = threadIdx.x, lane = t & 63, wv = t >> 6;
  int fr = lane & 15, quad = lane >> 4;
  int ga = wv >> 1, gb = wv & 1;
  int wm = ga * 64, wn = gb * 64;

  __shared__ u16 S[3 * 16 * 512];   // 3 buffers x 16 lines x 1KB = 48 KiB
  u16* Sb = S;

  // staging: wave wv owns lines wv*4 .. wv*4+3. Lines 0..7 = A(ga,i), 8..15 = B(gb,j).
  const u16* gsrc[4];
#pragma unroll
  for (int q = 0; q < 4; ++q) {
    int ls = wv * 4 + q;
    const u16* base;
    int lineIdx;
    if (ls < 8) {
      int g = ls >> 2, i = ls & 3;
      base = Xp; lineIdx = ((mt * 2 + g) * 4 + i) * 32;
    } else {
      int l2 = ls - 8;
      int g = l2 >> 2, j = l2 & 3;
      base = Wp; lineIdx = ((nt * 2 + g) * 4 + j) * 32;
    }
    gsrc[q] = base + (size_t)lineIdx * 512 + lane * 8;
  }

  f32x4 zero4 = {0.f, 0.f, 0.f, 0.f};
  f32x4 acc[4][4];
#pragma unroll
  for (int i = 0; i < 4; ++i)
#pragma unroll
    for (int j = 0; j < 4; ++j) acc[i][j] = zero4;

  KLOOP32;

  int h = (n0 + wn) >> 6;
#pragma unroll
  for (int i = 0; i < 4; ++i) {
    int rowbase = m0 + wm + i * 16 + quad * 4;
#pragma unroll
    for (int r = 0; r < 4; ++r) {
      int row = rowbase + r;
      if (row >= M_ROWS) continue;
      int b = row / SEQ;
      int sI = row - b * SEQ;
#pragma unroll
      for (int j = 0; j < 4; ++j) {
        int d = j * 16 + fr;
        float v = acc[i][j][r];
        float outv;
        if (mode == 2) {
          outv = v + bv[n0 + wn + d];
        } else {
          float vb = v;
          int jp = j ^ 2;
          float pv = acc[i][jp][r];
          if (mode == 0) {
            vb += bq[n0 + wn + d];
            pv += bq[n0 + wn + (jp * 16 + fr)];
          }
          if (sI >= NPREF) {
            int p = sI - NPREF;
            float c = rc[p * HD + d];
            float sn = rs[p * HD + d];
            float rot = (d < 32) ? -pv : pv;
            outv = vb * c + rot * sn;
          } else {
            outv = vb;
          }
          if (mode == 0) outv *= QSCALE;  // 0.125 * log2(e); attn uses exp2
        }
        dst[((size_t)(b * NH + h) * SEQ + sI) * HD + d] = f2bf(outv);
      }
    }
  }
}

// ---------------- flash attention; epilogue writes AO in packed-fragment layout ----------------
__global__ __launch_bounds__(256) void k_attn(
    const u16* __restrict__ Qg, const u16* __restrict__ Kg, const u16* __restrict__ Vg,
    u16* __restrict__ AOp)
{
  int bh = blockIdx.x;
  int mtb = blockIdx.y;
  int q0 = mtb * 128;
  int b = bh >> 4, h = bh & 15;
  const size_t base = (size_t)bh * SEQ * HD;

  __shared__ u16 KV[128 * APAD];
  __shared__ u16 Ps[4][32 * APAD];
  u16* Ks = KV;
  u16* Vt = KV + 64 * APAD;

  int t = threadIdx.x, lane = t & 63, wv = t >> 6;
  int fr = lane & 15, quad = lane >> 4;

  int ki = t >> 2;
  int kc0 = (t & 3) * 16;
  int vs0 = (t & 31) * 2;
  int vdo = (t >> 5) * 8;

  bf16x8 qf[2][2];
#pragma unroll
  for (int qt = 0; qt < 2; ++qt) {
#pragma unroll
    for (int st = 0; st < 2; ++st) {
      int row = q0 + wv * 32 + qt * 16 + fr;
      if (row >= SEQ) row = SEQ - 1;
      qf[qt][st] = *reinterpret_cast<const bf16x8*>(Qg + base + (size_t)row * HD + st * 32 + quad * 8);
    }
  }

  u16x8 one16 = {0x3F80, 0x3F80, 0x3F80, 0x3F80, 0x3F80, 0x3F80, 0x3F80, 0x3F80};
  bf16x8 vone = __builtin_bit_cast(bf16x8, one16);

  f32x4 zero4 = {0.f, 0.f, 0.f, 0.f};
  f32x4 o[2][5];
#pragma unroll
  for (int qt = 0; qt < 2; ++qt)
#pragma unroll
    for (int di = 0; di < 5; ++di) o[qt][di] = zero4;

  uint4 krA0, krA1, vrA0, vrA1;
  {
    int kr = ki; if (kr >= SEQ) kr = SEQ - 1;
    const u16* ksrc = Kg + base + (size_t)kr * HD;
    krA0 = *reinterpret_cast<const uint4*>(ksrc + kc0);
    krA1 = *reinterpret_cast<const uint4*>(ksrc + kc0 + 8);
    int r0 = vs0; if (r0 >= SEQ) r0 = SEQ - 1;
    int r1 = vs0 + 1; if (r1 >= SEQ) r1 = SEQ - 1;
    vrA0 = *reinterpret_cast<const uint4*>(Vg + base + (size_t)r0 * HD + vdo);
    vrA1 = *reinterpret_cast<const uint4*>(Vg + base + (size_t)r1 * HD + vdo);
  }

  for (int kt = 0; kt < 17; ++kt) {
    int k0 = kt * 64;
    BAR_LGKM;
    *reinterpret_cast<uint4*>(&Ks[ki * APAD + kc0]) = krA0;
    *reinterpret_cast<uint4*>(&Ks[ki * APAD + kc0 + 8]) = krA1;
    {
      u16 v0[8], v1[8];
      *reinterpret_cast<uint4*>(v0) = vrA0;
      *reinterpret_cast<uint4*>(v1) = vrA1;
#pragma unroll
      for (int j = 0; j < 8; ++j) {
        unsigned pk = (unsigned)v0[j] | ((unsigned)v1[j] << 16);
        *reinterpret_cast<unsigned*>(&Vt[(vdo + j) * APAD + vs0]) = pk;
      }
    }
    if (kt < 16) {
      int kn = k0 + 64;
      int kr = kn + ki; if (kr >= SEQ) kr = SEQ - 1;
      const u16* ksrc = Kg + base + (size_t)kr * HD;
      krA0 = *reinterpret_cast<const uint4*>(ksrc + kc0);
      krA1 = *reinterpret_cast<const uint4*>(ksrc + kc0 + 8);
      int r0 = kn + vs0; if (r0 >= SEQ) r0 = SEQ - 1;
      int r1 = kn + vs0 + 1; if (r1 >= SEQ) r1 = SEQ - 1;
      vrA0 = *reinterpret_cast<const uint4*>(Vg + base + (size_t)r0 * HD + vdo);
      vrA1 = *reinterpret_cast<const uint4*>(Vg + base + (size_t)r1 * HD + vdo);
    }
    BAR_LGKM;

    f32x4 sc[4][2];
#pragma unroll
    for (int mi = 0; mi < 4; ++mi)
#pragma unroll
      for (int qt = 0; qt < 2; ++qt) sc[mi][qt] = zero4;
    __builtin_amdgcn_s_setprio(1);
#pragma unroll
    for (int st = 0; st < 2; ++st) {
#pragma unroll
      for (int mi = 0; mi < 4; ++mi) {
        bf16x8 kf = *reinterpret_cast<const bf16x8*>(&Ks[(mi * 16 + fr) * APAD + st * 32 + quad * 8]);
#pragma unroll
        for (int qt = 0; qt < 2; ++qt)
          sc[mi][qt] = __builtin_amdgcn_mfma_f32_16x16x32_bf16(kf, qf[qt][st], sc[mi][qt], 0, 0, 0);
      }
    }
    __builtin_amdgcn_s_setprio(0);

    bool last = (kt == 16);
#pragma unroll
    for (int qt = 0; qt < 2; ++qt) {
#pragma unroll
      for (int mi = 0; mi < 4; ++mi) {
        float p0, p1, p2, p3;
        {
          float s0v = sc[mi][qt][0], s1v = sc[mi][qt][1], s2v = sc[mi][qt][2], s3v = sc[mi][qt][3];
          if (last) {
            int kc = mi * 16 + quad * 4;
            if (kc + 0 >= NPREF) s0v = -1e30f;
            if (kc + 1 >= NPREF) s1v = -1e30f;
            if (kc + 2 >= NPREF) s2v = -1e30f;
            if (kc + 3 >= NPREF) s3v = -1e30f;
          }
          // scores were computed with Q pre-scaled by 0.125*log2(e):
          // exp2(s' - 16*log2(e)) == exp(s_orig*0.125 - 16) exactly.
          p0 = exp2f(s0v - EXPBIAS);
          p1 = exp2f(s1v - EXPBIAS);
          p2 = exp2f(s2v - EXPBIAS);
          p3 = exp2f(s3v - EXPBIAS);
        }
        uint2 w;
        w.x = cvtpk(p0, p1);   // v_cvt_pk_bf16_f32: 1 op replaces 6-op sw RNE
        w.y = cvtpk(p2, p3);
        *reinterpret_cast<uint2*>(&Ps[wv][(qt * 16 + fr) * APAD + mi * 16 + quad * 4]) = w;
      }
    }

#pragma unroll
    for (int st = 0; st < 2; ++st) {
      bf16x8 pf[2];
#pragma unroll
      for (int qt = 0; qt < 2; ++qt)
        pf[qt] = *reinterpret_cast<const bf16x8*>(&Ps[wv][(qt * 16 + fr) * APAD + st * 32 + quad * 8]);
      __builtin_amdgcn_s_setprio(1);
#pragma unroll
      for (int di = 0; di < 4; ++di) {
        bf16x8 vf = *reinterpret_cast<const bf16x8*>(&Vt[(di * 16 + fr) * APAD + st * 32 + quad * 8]);
#pragma unroll
        for (int qt = 0; qt < 2; ++qt)
          o[qt][di] = __builtin_amdgcn_mfma_f32_16x16x32_bf16(pf[qt], vf, o[qt][di], 0, 0, 0);
      }
#pragma unroll
      for (int qt = 0; qt < 2; ++qt)
        o[qt][4] = __builtin_amdgcn_mfma_f32_16x16x32_bf16(pf[qt], vone, o[qt][4], 0, 0, 0);
      __builtin_amdgcn_s_setprio(0);
    }
  }

  __syncthreads();
#pragma unroll
  for (int qt = 0; qt < 2; ++qt) {
#pragma unroll
    for (int r = 0; r < 4; ++r) {
      int rowl = wv * 32 + qt * 16 + quad * 4 + r;
      bool valid = (q0 + rowl) < SEQ;
      float inv = valid ? (1.f / o[qt][4][r]) : 0.f;
#pragma unroll
      for (int di = 0; di < 4; ++di)
        KV[rowl * APAD + di * 16 + fr] = f2bf(o[qt][di][r] * inv);
    }
  }
  __syncthreads();
#pragma unroll
  for (int li = 0; li < 4; ++li) {
    int ll = wv * 4 + li;
    int g = ll >> 3, i = (ll >> 1) & 3, kkl = ll & 1;
    int rowl = g * 64 + i * 16 + (lane & 15);
    int col = kkl * 32 + (lane >> 4) * 8;
    uint4 d = *reinterpret_cast<const uint4*>(&KV[rowl * APAD + col]);
    size_t line = ((size_t)((b * 9 + mtb) * 2 + g) * 4 + i) * 32 + (h * 2 + kkl);
    *reinterpret_cast<uint4*>(AOp + line * 512 + lane * 8) = d;
  }
}

// ---------------- output GEMM: LDS-staged, pipelined (r5 form) ----------------
// grid 576: xcd=bid&7; s=bid>>3: nt fastest, mtq next; mid = mtq*8+xcd (exactly 72).
__global__ __launch_bounds__(256) void k_out(
    const u16* __restrict__ AOp, const u16* __restrict__ Po,
    const float* __restrict__ bo, float* __restrict__ Out)
{
  int bid = blockIdx.x;
  int xcd = bid & 7;
  int s = bid >> 3;           // 0..71
  int nt = s & 7;
  int mtq = s >> 3;           // 0..8
  int mid = mtq * 8 + xcd;    // 0..71
  int b = mid / 9, mtb = mid - b * 9;
  int n0 = nt * 128;

  int t = threadIdx.x, lane = t & 63, wv = t >> 6;
  int fr = lane & 15, quad = lane >> 4;
  int ga = wv >> 1, gb = wv & 1;
  int wm = ga * 64, wn = gb * 64;

  __shared__ u16 S[3 * 16 * 512];   // 48 KiB
  u16* Sb = S;

  const u16* gsrc[4];
#pragma unroll
  for (int q = 0; q < 4; ++q) {
    int ls = wv * 4 + q;
    const u16* base;
    int lineIdx;
    if (ls < 8) {
      int g = ls >> 2, i = ls & 3;
      base = AOp; lineIdx = ((mid * 2 + g) * 4 + i) * 32;
    } else {
      int l2 = ls - 8;
      int g = l2 >> 2, j = l2 & 3;
      base = Po; lineIdx = ((nt * 2 + g) * 4 + j) * 32;
    }
    gsrc[q] = base + (size_t)lineIdx * 512 + lane * 8;
  }

  f32x4 zero4 = {0.f, 0.f, 0.f, 0.f};
  f32x4 acc[4][4];
#pragma unroll
  for (int i = 0; i < 4; ++i)
#pragma unroll
    for (int j = 0; j < 4; ++j) acc[i][j] = zero4;

  KLOOP32;

#pragma unroll
  for (int i = 0; i < 4; ++i) {
    int rowbase = mtb * 128 + wm + i * 16 + quad * 4;
#pragma unroll
    for (int r = 0; r < 4; ++r) {
      int rowl = rowbase + r;
      if (rowl >= SEQ) continue;
      size_t row = (size_t)b * SEQ + rowl;
#pragma unroll
      for (int j = 0; j < 4; ++j) {
        int col = n0 + wn + j * 16 + fr;
        Out[row * DIMN + col] = acc[i][j][r] + bo[col];
      }
    }
  }
}

extern "C" void kernel_launch(void* const* d_in, const int* in_sizes, int n_in,
                              void* d_out, int out_size, void* d_ws, size_t ws_size,
                              hipStream_t stream)
{
  const float* x  = (const float*)d_in[0];
  const float* rc = (const float*)d_in[1];
  const float* rs = (const float*)d_in[2];
  const float* Wq = (const float*)d_in[3];
  const float* bq = (const float*)d_in[4];
  const float* Wk = (const float*)d_in[5];
  const float* Wv = (const float*)d_in[6];
  const float* bv = (const float*)d_in[7];
  const float* Wo = (const float*)d_in[8];
  const float* bo = (const float*)d_in[9];
  float* Out = (float*)d_out;

  u16* p = (u16*)d_ws;
  u16* Xp = p; p += (size_t)16640 * 512;
  u16* Pq = p; p += (size_t)2048 * 512;
  u16* Pk = p; p += (size_t)2048 * 512;
  u16* Pv = p; p += (size_t)2048 * 512;
  u16* Po = p; p += (size_t)2048 * 512;
  u16* Qg = p; p += (size_t)M_ROWS * DIMN;
  u16* Kg = p; p += (size_t)M_ROWS * DIMN;
  u16* Vg = p; p += (size_t)M_ROWS * DIMN;
  u16* AOp = Xp;  // aliases dead Xp+Pq after k_qkv

  dim3 gx(4, 130);
  k_pack_x<<<gx, 256, 0, stream>>>(x, Xp);
  dim3 gt(16, 16, 4);
  k_wt<<<gt, 256, 0, stream>>>(Wq, Wk, Wv, Wo, Pq, Pk, Pv, Po);
  k_qkv<<<1728, 256, 0, stream>>>(Xp, Pq, Pk, Pv, bq, bv, rc, rs, Qg, Kg, Vg);
  dim3 g2(128, 9);
  k_attn<<<g2, 256, 0, stream>>>(Qg, Kg, Vg, AOp);
  k_out<<<576, 256, 0, stream>>>(AOp, Po, bo, Out);
}

// Round 11
// 288.630 us; speedup vs baseline: 1.4766x; 1.0667x over previous
//
#include <hip/hip_runtime.h>

typedef unsigned short u16;
typedef __bf16 bf16x8 __attribute__((ext_vector_type(8)));
typedef unsigned short u16x8 __attribute__((ext_vector_type(8)));
typedef float f32x4 __attribute__((ext_vector_type(4)));

#define M_ROWS 8232
#define SEQ 1029
#define NPREF 5
#define DIMN 1024
#define NH 16
#define HD 64

// Q pre-scale = 0.125 * log2(e): lets attn use exp2 directly (saves a v_mul per score)
#define QSCALE 0.18033688011112042f
// 16 * log2(e)
#define EXPBIAS 23.083120654223414f

// k_attn LDS row pad: 72 u16 = 144 B. MUST stay 16B-aligned (multiple of 8 u16):
// r9 measured APAD=76 (152B, 8-mod-16) at 2x attn time -- misaligned b128.
// At 72, every b128 access is already at the 8-lanes/bank-group bandwidth
// minimum; the ~8.7M SQ_LDS_BANK_CONFLICT it reports is non-actionable (r9).
#define APAD 72

// raw barrier for attn: LDS-only wait, no vmem drain
#define BAR_LGKM asm volatile("s_waitcnt lgkmcnt(0)\ns_barrier" ::: "memory")

typedef __attribute__((address_space(1))) const unsigned char as1_u8;
typedef __attribute__((address_space(3))) unsigned char as3_u8;

// async global->LDS, 16B per lane. LDS dest is wave-uniform base + lane*16.
__device__ __forceinline__ void gload_lds16(const u16* g, u16* l) {
  __builtin_amdgcn_global_load_lds((as1_u8*)g, (as3_u8*)l, 16, 0, 0);
}

__device__ __forceinline__ u16 f2bf(float f) {
  unsigned u = __float_as_uint(f);
  u += 0x7fffu + ((u >> 16) & 1u);
  return (u16)(u >> 16);
}

// software packed f32x2 -> bf16x2 RNE. NOTE (r10): do NOT replace with
// inline-asm v_cvt_pk_bf16_f32 -- measured ~10% attn regression (asm pins
// regs / blocks scheduling; guide m240 says the same).
__device__ __forceinline__ unsigned pk2bf(float lo, float hi) {
  unsigned ul = __float_as_uint(lo);
  unsigned uh = __float_as_uint(hi);
  ul += 0x7fffu + ((ul >> 16) & 1u);
  uh += 0x7fffu + ((uh >> 16) & 1u);
  return __builtin_amdgcn_perm(uh, ul, 0x07060302u);
}

// ---------------- x (fp32) -> Xpack (bf16, fragment-major lines) ----------------
__global__ __launch_bounds__(256) void k_pack_x(const float* __restrict__ x, u16* __restrict__ Xp) {
  int cb = blockIdx.x;  // 0..3
  int rb = blockIdx.y;  // 0..129
  __shared__ u16 Tl[64 * 264];
  int t = threadIdx.x;
#pragma unroll
  for (int p = 0; p < 16; ++p) {
    int idx = p * 256 + t;
    int row = idx >> 6;
    int c4 = idx & 63;
    int grow = rb * 64 + row; if (grow >= M_ROWS) grow = M_ROWS - 1;
    float4 v = *reinterpret_cast<const float4*>(x + (size_t)grow * DIMN + cb * 256 + c4 * 4);
    ushort4 o;
    o.x = f2bf(v.x); o.y = f2bf(v.y); o.z = f2bf(v.z); o.w = f2bf(v.w);
    *reinterpret_cast<ushort4*>(&Tl[row * 264 + c4 * 4]) = o;
  }
  __syncthreads();
  int wv = t >> 6, lane = t & 63;
  int mt = rb >> 1, g = rb & 1;
#pragma unroll
  for (int li = 0; li < 8; ++li) {
    int ll = wv * 8 + li;
    int i = ll >> 3;
    int kkl = ll & 7;
    int row = i * 16 + (lane & 15);
    int col = kkl * 32 + (lane >> 4) * 8;
    uint4 d = *reinterpret_cast<const uint4*>(&Tl[row * 264 + col]);
    size_t line = ((size_t)(mt * 2 + g) * 4 + i) * 32 + (cb * 8 + kkl);
    *reinterpret_cast<uint4*>(Xp + line * 512 + lane * 8) = d;
  }
}

// ---------------- W (fp32 [K][N]) -> Wpack (bf16, fragment-major lines) ----------------
__global__ __launch_bounds__(256) void k_wt(const float* __restrict__ W0, const float* __restrict__ W1,
                                            const float* __restrict__ W2, const float* __restrict__ W3,
                                            u16* __restrict__ P0, u16* __restrict__ P1,
                                            u16* __restrict__ P2, u16* __restrict__ P3) {
  const float* W; u16* P;
  switch (blockIdx.z) {
    case 0: W = W0; P = P0; break;
    case 1: W = W1; P = P1; break;
    case 2: W = W2; P = P2; break;
    default: W = W3; P = P3; break;
  }
  __shared__ float tile[64 * 68];
  int t = threadIdx.x;
  int kb = blockIdx.x, nb = blockIdx.y;
#pragma unroll
  for (int p = 0; p < 16; ++p) {
    int idx = p * 256 + t;
    int row = idx >> 6, col = idx & 63;
    tile[row * 68 + col] = W[(size_t)(kb * 64 + row) * DIMN + nb * 64 + col];
  }
  __syncthreads();
  int wv = t >> 6, lane = t & 63;
#pragma unroll
  for (int li = 0; li < 2; ++li) {
    int ll = wv * 2 + li;
    int jg = ll >> 1, kkl = ll & 1;
    int n = jg * 16 + (lane & 15);
    int kc = kkl * 32 + (lane >> 4) * 8;
    u16 buf[8];
#pragma unroll
    for (int dk = 0; dk < 8; ++dk) buf[dk] = f2bf(tile[(kc + dk) * 68 + n]);
    size_t line = (size_t)(nb * 4 + jg) * 32 + kb * 2 + kkl;
    *reinterpret_cast<uint4*>(P + line * 512 + lane * 8) = *reinterpret_cast<const uint4*>(buf);
  }
}

#define MM16(AF, BF) do { \
  _Pragma("unroll") for (int i_ = 0; i_ < 4; ++i_) \
  _Pragma("unroll") for (int j_ = 0; j_ < 4; ++j_) \
    acc[i_][j_] = __builtin_amdgcn_mfma_f32_16x16x32_bf16(AF[i_], BF[j_], acc[i_][j_], 0, 0, 0); \
} while (0)

// stage tile tt into buffer bufI: each wave DMAs its 4 owned lines (4KB)
#define STAGE(bufI, tt) do { \
  _Pragma("unroll") for (int q_ = 0; q_ < 4; ++q_) \
    gload_lds16(gsrc[q_] + (size_t)(tt) * 512, Sb + (bufI) * 8192 + (wv * 4 + q_) * 512); \
} while (0)

// Pipelined K-loop (r5-verified best): 3 LDS buffers (48 KiB -> 3 blocks/CU),
// depth-2 prefetch, ONE barrier per K-step, STAGE issued AFTER the barrier.
// WAR: STAGE(t+2) writes buf (t-1)%3, whose readers all passed the top-of-t
// barrier before any wave issues STAGE(t+2). RAW: staging wave waits vmcnt(4)
// before the iter-t barrier, draining buf-t's DMA. Tail: last STAGE at kk=29;
// kk=31 waits vmcnt(0) -> zero outstanding LDS-DMA at exit (in-flight DMA at
// s_endpgm hangs). setprio(1) around MFMA cluster (T5, multi-block/CU regime).
#define KLOOP32 do { \
  STAGE(0, 0); \
  STAGE(1, 1); \
  _Pragma("unroll") \
  for (int kk = 0; kk < 32; ++kk) { \
    if (kk < 31) { \
      asm volatile("s_waitcnt vmcnt(4)" ::: "memory"); \
    } else { \
      asm volatile("s_waitcnt vmcnt(0)" ::: "memory"); \
    } \
    __builtin_amdgcn_s_barrier(); \
    asm volatile("" ::: "memory"); \
    if (kk + 2 < 32) STAGE((kk + 2) % 3, kk + 2); \
    const u16* rd_ = Sb + (kk % 3) * 8192; \
    bf16x8 a_[4], bfr_[4]; \
    _Pragma("unroll") for (int i_ = 0; i_ < 4; ++i_) { \
      a_[i_]   = *reinterpret_cast<const bf16x8*>(rd_ + (ga * 4 + i_) * 512 + lane * 8); \
      bfr_[i_] = *reinterpret_cast<const bf16x8*>(rd_ + (8 + gb * 4 + i_) * 512 + lane * 8); \
    } \
    __builtin_amdgcn_s_setprio(1); \
    MM16(a_, bfr_); \
    __builtin_amdgcn_s_setprio(0); \
    asm volatile("" ::: "memory"); \
  } \
} while (0)

// ---------------- fused QKV projection GEMM: 128x128, LDS-staged, pipelined (r5 form) ----------------
// grid 1728: xcd=bid&7; within XCD: nt fastest (A-tile sharers), then mtq (A stream),
// then mode slowest (2MB weight pack L2-resident per phase). mt = mtq*8+xcd.
__global__ __launch_bounds__(256) void k_qkv(
    const u16* __restrict__ Xp,
    const u16* __restrict__ Pq, const u16* __restrict__ Pk, const u16* __restrict__ Pv,
    const float* __restrict__ bq, const float* __restrict__ bv,
    const float* __restrict__ rc, const float* __restrict__ rs,
    u16* __restrict__ Qg, u16* __restrict__ Kg, u16* __restrict__ Vg)
{
  int bid = blockIdx.x;
  int xcd = bid & 7;
  int s = bid >> 3;           // 0..215
  int nt = s & 7;
  int s2 = s >> 3;            // 0..26
  int mode = s2 / 9;
  int mtq = s2 - mode * 9;
  int mt = mtq * 8 + xcd;
  if (mt >= 65) return;
  const u16* Wp = (mode == 0) ? Pq : (mode == 1) ? Pk : Pv;
  u16* dst = (mode == 0) ? Qg : (mode == 1) ? Kg : Vg;
  int m0 = mt * 128, n0 = nt * 128;

  int t = threadIdx.x, lane = t & 63, wv = t >> 6;
  int fr = lane & 15, quad = lane >> 4;
  int ga = wv >> 1, gb = wv & 1;
  int wm = ga * 64, wn = gb * 64;

  __shared__ u16 S[3 * 16 * 512];   // 3 buffers x 16 lines x 1KB = 48 KiB
  u16* Sb = S;

  // staging: wave wv owns lines wv*4 .. wv*4+3. Lines 0..7 = A(ga,i), 8..15 = B(gb,j).
  const u16* gsrc[4];
#pragma unroll
  for (int q = 0; q < 4; ++q) {
    int ls = wv * 4 + q;
    const u16* base;
    int lineIdx;
    if (ls < 8) {
      int g = ls >> 2, i = ls & 3;
      base = Xp; lineIdx = ((mt * 2 + g) * 4 + i) * 32;
    } else {
      int l2 = ls - 8;
      int g = l2 >> 2, j = l2 & 3;
      base = Wp; lineIdx = ((nt * 2 + g) * 4 + j) * 32;
    }
    gsrc[q] = base + (size_t)lineIdx * 512 + lane * 8;
  }

  f32x4 zero4 = {0.f, 0.f, 0.f, 0.f};
  f32x4 acc[4][4];
#pragma unroll
  for (int i = 0; i < 4; ++i)
#pragma unroll
    for (int j = 0; j < 4; ++j) acc[i][j] = zero4;

  KLOOP32;

  int h = (n0 + wn) >> 6;
#pragma unroll
  for (int i = 0; i < 4; ++i) {
    int rowbase = m0 + wm + i * 16 + quad * 4;
#pragma unroll
    for (int r = 0; r < 4; ++r) {
      int row = rowbase + r;
      if (row >= M_ROWS) continue;
      int b = row / SEQ;
      int sI = row - b * SEQ;
#pragma unroll
      for (int j = 0; j < 4; ++j) {
        int d = j * 16 + fr;
        float v = acc[i][j][r];
        float outv;
        if (mode == 2) {
          outv = v + bv[n0 + wn + d];
        } else {
          float vb = v;
          int jp = j ^ 2;
          float pv = acc[i][jp][r];
          if (mode == 0) {
            vb += bq[n0 + wn + d];
            pv += bq[n0 + wn + (jp * 16 + fr)];
          }
          if (sI >= NPREF) {
            int p = sI - NPREF;
            float c = rc[p * HD + d];
            float sn = rs[p * HD + d];
            float rot = (d < 32) ? -pv : pv;
            outv = vb * c + rot * sn;
          } else {
            outv = vb;
          }
          if (mode == 0) outv *= QSCALE;  // 0.125 * log2(e); attn uses exp2
        }
        dst[((size_t)(b * NH + h) * SEQ + sI) * HD + d] = f2bf(outv);
      }
    }
  }
}

// ---------------- flash attention; epilogue writes AO in packed-fragment layout ----------------
__global__ __launch_bounds__(256) void k_attn(
    const u16* __restrict__ Qg, const u16* __restrict__ Kg, const u16* __restrict__ Vg,
    u16* __restrict__ AOp)
{
  int bh = blockIdx.x;
  int mtb = blockIdx.y;
  int q0 = mtb * 128;
  int b = bh >> 4, h = bh & 15;
  const size_t base = (size_t)bh * SEQ * HD;

  __shared__ u16 KV[128 * APAD];
  __shared__ u16 Ps[4][32 * APAD];
  u16* Ks = KV;
  u16* Vt = KV + 64 * APAD;

  int t = threadIdx.x, lane = t & 63, wv = t >> 6;
  int fr = lane & 15, quad = lane >> 4;

  int ki = t >> 2;
  int kc0 = (t & 3) * 16;
  int vs0 = (t & 31) * 2;
  int vdo = (t >> 5) * 8;

  bf16x8 qf[2][2];
#pragma unroll
  for (int qt = 0; qt < 2; ++qt) {
#pragma unroll
    for (int st = 0; st < 2; ++st) {
      int row = q0 + wv * 32 + qt * 16 + fr;
      if (row >= SEQ) row = SEQ - 1;
      qf[qt][st] = *reinterpret_cast<const bf16x8*>(Qg + base + (size_t)row * HD + st * 32 + quad * 8);
    }
  }

  u16x8 one16 = {0x3F80, 0x3F80, 0x3F80, 0x3F80, 0x3F80, 0x3F80, 0x3F80, 0x3F80};
  bf16x8 vone = __builtin_bit_cast(bf16x8, one16);

  f32x4 zero4 = {0.f, 0.f, 0.f, 0.f};
  f32x4 o[2][5];
#pragma unroll
  for (int qt = 0; qt < 2; ++qt)
#pragma unroll
    for (int di = 0; di < 5; ++di) o[qt][di] = zero4;

  uint4 krA0, krA1, vrA0, vrA1;
  {
    int kr = ki; if (kr >= SEQ) kr = SEQ - 1;
    const u16* ksrc = Kg + base + (size_t)kr * HD;
    krA0 = *reinterpret_cast<const uint4*>(ksrc + kc0);
    krA1 = *reinterpret_cast<const uint4*>(ksrc + kc0 + 8);
    int r0 = vs0; if (r0 >= SEQ) r0 = SEQ - 1;
    int r1 = vs0 + 1; if (r1 >= SEQ) r1 = SEQ - 1;
    vrA0 = *reinterpret_cast<const uint4*>(Vg + base + (size_t)r0 * HD + vdo);
    vrA1 = *reinterpret_cast<const uint4*>(Vg + base + (size_t)r1 * HD + vdo);
  }

  for (int kt = 0; kt < 17; ++kt) {
    int k0 = kt * 64;
    BAR_LGKM;
    *reinterpret_cast<uint4*>(&Ks[ki * APAD + kc0]) = krA0;
    *reinterpret_cast<uint4*>(&Ks[ki * APAD + kc0 + 8]) = krA1;
    {
      u16 v0[8], v1[8];
      *reinterpret_cast<uint4*>(v0) = vrA0;
      *reinterpret_cast<uint4*>(v1) = vrA1;
#pragma unroll
      for (int j = 0; j < 8; ++j) {
        unsigned pk = (unsigned)v0[j] | ((unsigned)v1[j] << 16);
        *reinterpret_cast<unsigned*>(&Vt[(vdo + j) * APAD + vs0]) = pk;
      }
    }
    if (kt < 16) {
      int kn = k0 + 64;
      int kr = kn + ki; if (kr >= SEQ) kr = SEQ - 1;
      const u16* ksrc = Kg + base + (size_t)kr * HD;
      krA0 = *reinterpret_cast<const uint4*>(ksrc + kc0);
      krA1 = *reinterpret_cast<const uint4*>(ksrc + kc0 + 8);
      int r0 = kn + vs0; if (r0 >= SEQ) r0 = SEQ - 1;
      int r1 = kn + vs0 + 1; if (r1 >= SEQ) r1 = SEQ - 1;
      vrA0 = *reinterpret_cast<const uint4*>(Vg + base + (size_t)r0 * HD + vdo);
      vrA1 = *reinterpret_cast<const uint4*>(Vg + base + (size_t)r1 * HD + vdo);
    }
    BAR_LGKM;

    f32x4 sc[4][2];
#pragma unroll
    for (int mi = 0; mi < 4; ++mi)
#pragma unroll
      for (int qt = 0; qt < 2; ++qt) sc[mi][qt] = zero4;
    __builtin_amdgcn_s_setprio(1);
#pragma unroll
    for (int st = 0; st < 2; ++st) {
#pragma unroll
      for (int mi = 0; mi < 4; ++mi) {
        bf16x8 kf = *reinterpret_cast<const bf16x8*>(&Ks[(mi * 16 + fr) * APAD + st * 32 + quad * 8]);
#pragma unroll
        for (int qt = 0; qt < 2; ++qt)
          sc[mi][qt] = __builtin_amdgcn_mfma_f32_16x16x32_bf16(kf, qf[qt][st], sc[mi][qt], 0, 0, 0);
      }
    }
    __builtin_amdgcn_s_setprio(0);

    bool last = (kt == 16);
#pragma unroll
    for (int qt = 0; qt < 2; ++qt) {
#pragma unroll
      for (int mi = 0; mi < 4; ++mi) {
        float p0, p1, p2, p3;
        {
          float s0v = sc[mi][qt][0], s1v = sc[mi][qt][1], s2v = sc[mi][qt][2], s3v = sc[mi][qt][3];
          if (last) {
            int kc = mi * 16 + quad * 4;
            if (kc + 0 >= NPREF) s0v = -1e30f;
            if (kc + 1 >= NPREF) s1v = -1e30f;
            if (kc + 2 >= NPREF) s2v = -1e30f;
            if (kc + 3 >= NPREF) s3v = -1e30f;
          }
          // scores were computed with Q pre-scaled by 0.125*log2(e):
          // exp2(s' - 16*log2(e)) == exp(s_orig*0.125 - 16) exactly.
          p0 = __builtin_amdgcn_exp2f(s0v - EXPBIAS);
          p1 = __builtin_amdgcn_exp2f(s1v - EXPBIAS);
          p2 = __builtin_amdgcn_exp2f(s2v - EXPBIAS);
          p3 = __builtin_amdgcn_exp2f(s3v - EXPBIAS);
        }
        unsigned d0 = pk2bf(p0, p1);
        unsigned d1 = pk2bf(p2, p3);
        uint2 w; w.x = d0; w.y = d1;
        *reinterpret_cast<uint2*>(&Ps[wv][(qt * 16 + fr) * APAD + mi * 16 + quad * 4]) = w;
      }
    }

#pragma unroll
    for (int st = 0; st < 2; ++st) {
      bf16x8 pf[2];
#pragma unroll
      for (int qt = 0; qt < 2; ++qt)
        pf[qt] = *reinterpret_cast<const bf16x8*>(&Ps[wv][(qt * 16 + fr) * APAD + st * 32 + quad * 8]);
      __builtin_amdgcn_s_setprio(1);
#pragma unroll
      for (int di = 0; di < 4; ++di) {
        bf16x8 vf = *reinterpret_cast<const bf16x8*>(&Vt[(di * 16 + fr) * APAD + st * 32 + quad * 8]);
#pragma unroll
        for (int qt = 0; qt < 2; ++qt)
          o[qt][di] = __builtin_amdgcn_mfma_f32_16x16x32_bf16(pf[qt], vf, o[qt][di], 0, 0, 0);
      }
#pragma unroll
      for (int qt = 0; qt < 2; ++qt)
        o[qt][4] = __builtin_amdgcn_mfma_f32_16x16x32_bf16(pf[qt], vone, o[qt][4], 0, 0, 0);
      __builtin_amdgcn_s_setprio(0);
    }
  }

  __syncthreads();
#pragma unroll
  for (int qt = 0; qt < 2; ++qt) {
#pragma unroll
    for (int r = 0; r < 4; ++r) {
      int rowl = wv * 32 + qt * 16 + quad * 4 + r;
      bool valid = (q0 + rowl) < SEQ;
      float inv = valid ? (1.f / o[qt][4][r]) : 0.f;
#pragma unroll
      for (int di = 0; di < 4; ++di)
        KV[rowl * APAD + di * 16 + fr] = f2bf(o[qt][di][r] * inv);
    }
  }
  __syncthreads();
#pragma unroll
  for (int li = 0; li < 4; ++li) {
    int ll = wv * 4 + li;
    int g = ll >> 3, i = (ll >> 1) & 3, kkl = ll & 1;
    int rowl = g * 64 + i * 16 + (lane & 15);
    int col = kkl * 32 + (lane >> 4) * 8;
    uint4 d = *reinterpret_cast<const uint4*>(&KV[rowl * APAD + col]);
    size_t line = ((size_t)((b * 9 + mtb) * 2 + g) * 4 + i) * 32 + (h * 2 + kkl);
    *reinterpret_cast<uint4*>(AOp + line * 512 + lane * 8) = d;
  }
}

// ---------------- output GEMM: LDS-staged, pipelined (r5 form) ----------------
// grid 576: xcd=bid&7; s=bid>>3: nt fastest, mtq next; mid = mtq*8+xcd (exactly 72).
__global__ __launch_bounds__(256) void k_out(
    const u16* __restrict__ AOp, const u16* __restrict__ Po,
    const float* __restrict__ bo, float* __restrict__ Out)
{
  int bid = blockIdx.x;
  int xcd = bid & 7;
  int s = bid >> 3;           // 0..71
  int nt = s & 7;
  int mtq = s >> 3;           // 0..8
  int mid = mtq * 8 + xcd;    // 0..71
  int b = mid / 9, mtb = mid - b * 9;
  int n0 = nt * 128;

  int t = threadIdx.x, lane = t & 63, wv = t >> 6;
  int fr = lane & 15, quad = lane >> 4;
  int ga = wv >> 1, gb = wv & 1;
  int wm = ga * 64, wn = gb * 64;

  __shared__ u16 S[3 * 16 * 512];   // 48 KiB
  u16* Sb = S;

  const u16* gsrc[4];
#pragma unroll
  for (int q = 0; q < 4; ++q) {
    int ls = wv * 4 + q;
    const u16* base;
    int lineIdx;
    if (ls < 8) {
      int g = ls >> 2, i = ls & 3;
      base = AOp; lineIdx = ((mid * 2 + g) * 4 + i) * 32;
    } else {
      int l2 = ls - 8;
      int g = l2 >> 2, j = l2 & 3;
      base = Po; lineIdx = ((nt * 2 + g) * 4 + j) * 32;
    }
    gsrc[q] = base + (size_t)lineIdx * 512 + lane * 8;
  }

  f32x4 zero4 = {0.f, 0.f, 0.f, 0.f};
  f32x4 acc[4][4];
#pragma unroll
  for (int i = 0; i < 4; ++i)
#pragma unroll
    for (int j = 0; j < 4; ++j) acc[i][j] = zero4;

  KLOOP32;

#pragma unroll
  for (int i = 0; i < 4; ++i) {
    int rowbase = mtb * 128 + wm + i * 16 + quad * 4;
#pragma unroll
    for (int r = 0; r < 4; ++r) {
      int rowl = rowbase + r;
      if (rowl >= SEQ) continue;
      size_t row = (size_t)b * SEQ + rowl;
#pragma unroll
      for (int j = 0; j < 4; ++j) {
        int col = n0 + wn + j * 16 + fr;
        Out[row * DIMN + col] = acc[i][j][r] + bo[col];
      }
    }
  }
}

extern "C" void kernel_launch(void* const* d_in, const int* in_sizes, int n_in,
                              void* d_out, int out_size, void* d_ws, size_t ws_size,
                              hipStream_t stream)
{
  const float* x  = (const float*)d_in[0];
  const float* rc = (const float*)d_in[1];
  const float* rs = (const float*)d_in[2];
  const float* Wq = (const float*)d_in[3];
  const float* bq = (const float*)d_in[4];
  const float* Wk = (const float*)d_in[5];
  const float* Wv = (const float*)d_in[6];
  const float* bv = (const float*)d_in[7];
  const float* Wo = (const float*)d_in[8];
  const float* bo = (const float*)d_in[9];
  float* Out = (float*)d_out;

  u16* p = (u16*)d_ws;
  u16* Xp = p; p += (size_t)16640 * 512;
  u16* Pq = p; p += (size_t)2048 * 512;
  u16* Pk = p; p += (size_t)2048 * 512;
  u16* Pv = p; p += (size_t)2048 * 512;
  u16* Po = p; p += (size_t)2048 * 512;
  u16* Qg = p; p += (size_t)M_ROWS * DIMN;
  u16* Kg = p; p += (size_t)M_ROWS * DIMN;
  u16* Vg = p; p += (size_t)M_ROWS * DIMN;
  u16* AOp = Xp;  // aliases dead Xp+Pq after k_qkv

  dim3 gx(4, 130);
  k_pack_x<<<gx, 256, 0, stream>>>(x, Xp);
  dim3 gt(16, 16, 4);
  k_wt<<<gt, 256, 0, stream>>>(Wq, Wk, Wv, Wo, Pq, Pk, Pv, Po);
  k_qkv<<<1728, 256, 0, stream>>>(Xp, Pq, Pk, Pv, bq, bv, rc, rs, Qg, Kg, Vg);
  dim3 g2(128, 9);
  k_attn<<<g2, 256, 0, stream>>>(Qg, Kg, Vg, AOp);
  k_out<<<576, 256, 0, stream>>>(AOp, Po, bo, Out);
}